// Round 20
// baseline (99.217 us; speedup 1.0000x reference)
//
#include <hip/hip_runtime.h>
#include <hip/hip_bf16.h>
#include <math.h>

// Problem: B=1, T=2048, E=1024, H=16, DH=64, NB=10, ML=2048
// Pipeline (all bf16 MFMA), 4 kernels:
//   prep_mega: Xb = bf16(X); WbT = [Wq*0.125*log2e|Wk|Wv|Wr]^T (rows<3232);
//              WpT; bias; BndT*log2e (in WbT pad rows - only BndT writes there)
//   gemm64 (64x128, 832 blocks): Y = Xb @ Wb + bias; V-col blocks also emit
//              Vt[h][d][t] transposed in the epilogue
//   attn: r18 structure + SPLIT DRAIN: issue K(8)|bw(5)|V(8), wait vmcnt(13)
//         before S, auto vmcnt(8) at E, vmcnt(0) only before PV
//   gemm64 (64x128, 256 blocks): out = AO @ Wp + bp (f32)

typedef __attribute__((ext_vector_type(8))) short bf16x8;
typedef __attribute__((ext_vector_type(4))) float f32x4;
typedef unsigned long long __attribute__((may_alias)) u64a;

#define MFMA16(a,b,c) __builtin_amdgcn_mfma_f32_16x16x32_bf16((a),(b),(c),0,0,0)
#define GLB(p)  ((const __attribute__((address_space(1))) void*)(p))
#define LDSP(p) ((__attribute__((address_space(3))) void*)(p))
#define LDY2 3328
#define LOG2E 1.44269504088896f

__device__ __forceinline__ unsigned short f2bf(float x){
  unsigned u = __float_as_uint(x);
  u = (u + 0x7FFFu + ((u >> 16) & 1u)) >> 16;
  return (unsigned short)u;
}
__device__ __forceinline__ unsigned short f2bf_rn(float x){
  __hip_bfloat16 b = __float2bfloat16(x);
  return *reinterpret_cast<unsigned short*>(&b);
}
__device__ __forceinline__ float bf2f(unsigned short b){
  return __uint_as_float(((unsigned)b) << 16);
}

// -------- prep kernel (convert_x | pack_wbt | transpose_wp | bias | bndt) ----

__global__ __launch_bounds__(256) void prep_mega(
    const float* __restrict__ X,
    const float* __restrict__ Wq, const float* __restrict__ Wk,
    const float* __restrict__ Wv, const float* __restrict__ Wr,
    const float* __restrict__ Wp,
    const float* __restrict__ bq, const float* __restrict__ br,
    const float* __restrict__ bnd,
    unsigned short* __restrict__ Xb, unsigned short* __restrict__ WbT,
    unsigned short* __restrict__ WpT, float* __restrict__ bias,
    unsigned short* __restrict__ BndT)
{
  __shared__ float tile[64][65];
  const int b = blockIdx.x;
  const int tid = threadIdx.x;

  if (b < 1024){
    const int i = (b * 256 + tid) * 8;
    f32x4 a = *(const f32x4*)(X + i);
    f32x4 v2 = *(const f32x4*)(X + i + 4);
    bf16x8 v;
    v[0]=(short)f2bf(a.x); v[1]=(short)f2bf(a.y); v[2]=(short)f2bf(a.z); v[3]=(short)f2bf(a.w);
    v[4]=(short)f2bf(v2.x); v[5]=(short)f2bf(v2.y); v[6]=(short)f2bf(v2.z); v[7]=(short)f2bf(v2.w);
    *(bf16x8*)(Xb + i) = v;
    return;
  }
  if (b < 1024 + 832){
    const int idx = b - 1024;
    const int k0 = (idx & 15) * 64, c0 = (idx >> 4) * 64;
    {
      const int r = tid >> 2, cs = (tid & 3) << 4;
      #pragma unroll
      for (int q = 0; q < 4; ++q){
        const int c = c0 + cs + q * 4;
        f32x4 v;
        if (c < 1024){
          v = *(const f32x4*)(Wq + (size_t)(k0+r)*1024 + c);
          const float s = 0.125f * LOG2E;
          v.x *= s; v.y *= s; v.z *= s; v.w *= s;
        }
        else if (c < 2048) v = *(const f32x4*)(Wk + (size_t)(k0+r)*1024 + (c-1024));
        else if (c < 3072) v = *(const f32x4*)(Wv + (size_t)(k0+r)*1024 + (c-2048));
        else if (c < 3232) v = *(const f32x4*)(Wr + (size_t)(k0+r)*160  + (c-3072));
        else               v = (f32x4){0.f,0.f,0.f,0.f};
        tile[r][cs+q*4+0]=v.x; tile[r][cs+q*4+1]=v.y; tile[r][cs+q*4+2]=v.z; tile[r][cs+q*4+3]=v.w;
      }
    }
    __syncthreads();
    const int c = tid >> 2, ks = (tid & 3) << 4;
    if (c0 + c < 3232){     // rows >= 3232 belong to BndT
      bf16x8 o0, o1;
      #pragma unroll
      for (int x = 0; x < 8; ++x) o0[x] = (short)f2bf(tile[ks + x][c]);
      #pragma unroll
      for (int x = 0; x < 8; ++x) o1[x] = (short)f2bf(tile[ks + 8 + x][c]);
      *(bf16x8*)(WbT + (size_t)(c0 + c) * 1024 + k0 + ks)     = o0;
      *(bf16x8*)(WbT + (size_t)(c0 + c) * 1024 + k0 + ks + 8) = o1;
    }
    return;
  }
  if (b < 1024 + 832 + 256){
    const int idx = b - 1856;
    const int k0 = (idx & 15) * 64, c0 = (idx >> 4) * 64;
    {
      const int r = tid >> 2, cs = (tid & 3) << 4;
      #pragma unroll
      for (int q = 0; q < 4; ++q){
        f32x4 v = *(const f32x4*)(Wp + (size_t)(k0+r)*1024 + c0 + cs + q*4);
        tile[r][cs+q*4+0]=v.x; tile[r][cs+q*4+1]=v.y; tile[r][cs+q*4+2]=v.z; tile[r][cs+q*4+3]=v.w;
      }
    }
    __syncthreads();
    const int c = tid >> 2, ks = (tid & 3) << 4;
    bf16x8 o0, o1;
    #pragma unroll
    for (int x = 0; x < 8; ++x) o0[x] = (short)f2bf(tile[ks + x][c]);
    #pragma unroll
    for (int x = 0; x < 8; ++x) o1[x] = (short)f2bf(tile[ks + 8 + x][c]);
    *(bf16x8*)(WpT + (size_t)(c0 + c) * 1024 + k0 + ks)     = o0;
    *(bf16x8*)(WpT + (size_t)(c0 + c) * 1024 + k0 + ks + 8) = o1;
    return;
  }
  if (b < 2125){
    const int c = (b - 2112) * 256 + tid;
    if (c < 3328){
      float v = 0.f;
      if (c < 1024) v = bq[c] * 0.125f * LOG2E;
      else if (c >= 3072 && c < 3232) v = br[c - 3072];
      bias[c] = v;
    }
    return;
  }
  const int t = (b - 2125) * 256 + tid;
  if (t >= 2176) return;
  const int rel = t - 64;
  unsigned short* dst = BndT + (size_t)t * 32;
  bf16x8 v0 = {}, v1 = {}, z = {};
  if (rel >= 0 && rel < 2048){
    #pragma unroll
    for (int n = 0; n < 8; ++n) v0[n] = (short)f2bf(bnd[n * 2048 + rel] * LOG2E);
    v1[0] = (short)f2bf(bnd[8 * 2048 + rel] * LOG2E);
    v1[1] = (short)f2bf(bnd[9 * 2048 + rel] * LOG2E);
  }
  *(bf16x8*)dst        = v0;
  *(bf16x8*)(dst + 8)  = v1;
  *(bf16x8*)(dst + 16) = z;
  *(bf16x8*)(dst + 24) = z;
}

// ---------------- bf16 MFMA GEMM, 64x128 tile (unified) ---------------------

__global__ __launch_bounds__(256) void gemm64(
    const unsigned short* __restrict__ A,
    const unsigned short* __restrict__ BT,
    const float* __restrict__ bias,
    void* __restrict__ C, int ldc, int out_f32,
    unsigned short* __restrict__ VtOut)
{
  __shared__ unsigned short As[64 * 64];
  __shared__ unsigned short Bs[128 * 64];
  const int tid = threadIdx.x;
  const int w = tid >> 6, lane = tid & 63;
  const int lid = lane & 15, lgrp = lane >> 4;
  const int wm = w >> 1, wn = w & 1;
  const int row0 = blockIdx.y << 6, col0 = blockIdx.x << 7;
  const int sr = lane >> 3;
  const int sc = (lane & 7) ^ sr;
  const bool do_vt = (VtOut != nullptr) && (col0 >= 2048) && (col0 < 3072);

  f32x4 acc[2][4] = {};

  for (int k0 = 0; k0 < 1024; k0 += 64){
    #pragma unroll
    for (int it = 0; it < 2; ++it){
      const int r0w = (w << 4) + (it << 3);
      const int r = r0w + sr;
      __builtin_amdgcn_global_load_lds(GLB(A + (size_t)(row0 + r) * 1024 + k0 + (sc << 3)),
                                       LDSP(&As[r0w << 6]), 16, 0, 0);
    }
    #pragma unroll
    for (int it = 0; it < 4; ++it){
      const int r0w = (w << 5) + (it << 3);
      const int r = r0w + sr;
      __builtin_amdgcn_global_load_lds(GLB(BT + (size_t)(col0 + r) * 1024 + k0 + (sc << 3)),
                                       LDSP(&Bs[r0w << 6]), 16, 0, 0);
    }
    __syncthreads();

    bf16x8 af[2][2], bfr[4][2];
    #pragma unroll
    for (int m = 0; m < 2; ++m){
      const int ra = wm * 32 + m * 16 + lid;
      #pragma unroll
      for (int kk = 0; kk < 2; ++kk){
        const int kc = kk * 4 + lgrp;
        af[m][kk] = *(const bf16x8*)&As[(ra << 6) + ((kc ^ (lid & 7)) << 3)];
      }
    }
    #pragma unroll
    for (int n = 0; n < 4; ++n){
      const int rb = wn * 64 + n * 16 + lid;
      #pragma unroll
      for (int kk = 0; kk < 2; ++kk){
        const int kc = kk * 4 + lgrp;
        bfr[n][kk] = *(const bf16x8*)&Bs[(rb << 6) + ((kc ^ (lid & 7)) << 3)];
      }
    }
    #pragma unroll
    for (int m = 0; m < 2; ++m)
      #pragma unroll
      for (int n = 0; n < 4; ++n){
        acc[m][n] = MFMA16(af[m][0], bfr[n][0], acc[m][n]);
        acc[m][n] = MFMA16(af[m][1], bfr[n][1], acc[m][n]);
      }
    __syncthreads();
  }

  #pragma unroll
  for (int m = 0; m < 2; ++m){
    #pragma unroll
    for (int n = 0; n < 4; ++n){
      const int col = col0 + wn * 64 + n * 16 + lid;
      const float bv = bias[col];
      const int rowb = row0 + wm * 32 + m * 16 + lgrp * 4;
      unsigned short bf[4];
      #pragma unroll
      for (int i = 0; i < 4; ++i){
        const float v = acc[m][n][i] + bv;
        if (out_f32) ((float*)C)[(size_t)(rowb + i) * ldc + col] = v;
        else {
          bf[i] = f2bf(v);
          ((unsigned short*)C)[(size_t)(rowb + i) * ldc + col] = bf[i];
        }
      }
      if (do_vt){
        const unsigned long long pk =
            ((unsigned long long)bf[0])        | (((unsigned long long)bf[1]) << 16) |
            (((unsigned long long)bf[2]) << 32) | (((unsigned long long)bf[3]) << 48);
        *(u64a*)(VtOut + (size_t)(col - 2048) * 2048 + rowb) = pk;
      }
    }
  }
}

// ---------------- fused flash attention (r19 + split vmcnt drain) ------------

template<bool DIAG>
__device__ __forceinline__ void attn_tile_body(
    const unsigned short* __restrict__ Ksb,
    const unsigned short* __restrict__ Vsb,
    unsigned short* __restrict__ un,
    const bf16x8 (&bw)[5],
    const bf16x8 (&qf)[2], const bf16x8& rf,
    int lid, int lgrp, int ql,
    float& m_i, float& l_i, f32x4 (&o)[4])
{
  // S^T = K Q^T (Ks landed: caller waited vmcnt(13))
  f32x4 s[4] = {};
  __builtin_amdgcn_s_setprio(1);
  #pragma unroll
  for (int kk = 0; kk < 2; ++kk){
    const int kc = kk * 4 + lgrp;
    #pragma unroll
    for (int n4 = 0; n4 < 4; ++n4){
      const bf16x8 kf = *(const bf16x8*)&Ksb[((n4*16 + lid) << 6) + ((kc ^ (lid & 7)) << 3)];
      s[n4] = MFMA16(kf, qf[kk], s[n4]);
    }
  }
  __builtin_amdgcn_s_setprio(0);

  // E window via MFMA (compiler auto-waits vmcnt(8) for bw; V stays in flight)
  #pragma unroll
  for (int f = 0; f < 5; ++f){
    f32x4 ef = {};
    ef = MFMA16(rf, bw[f], ef);
    const unsigned lo = ((unsigned)f2bf_rn(ef[0])) | (((unsigned)f2bf_rn(ef[1])) << 16);
    const unsigned hi = ((unsigned)f2bf_rn(ef[2])) | (((unsigned)f2bf_rn(ef[3])) << 16);
    const unsigned long long pk = ((unsigned long long)hi << 32) | lo;
    *(u64a*)&un[(f*16 + lid) * 20 + lgrp*4] = pk;
  }

  // bias gather (+ causal mask on the diagonal tile only)
  #pragma unroll
  for (int n4 = 0; n4 < 4; ++n4){
    #pragma unroll
    for (int i = 0; i < 4; ++i){
      const int jl = n4*16 + lgrp*4 + i;
      float v = s[n4][i] + bf2f(un[(lid - jl + 63) * 20 + lid]);
      if (DIAG && jl > ql) v = -1e9f;
      s[n4][i] = v;
    }
  }

  // in-register online softmax (exp2 domain), defer-max THR = 8*log2e
  float rm = s[0][0];
  #pragma unroll
  for (int n4 = 0; n4 < 4; ++n4)
    #pragma unroll
    for (int i = 0; i < 4; ++i) rm = fmaxf(rm, s[n4][i]);
  rm = fmaxf(rm, __shfl_xor(rm, 16));
  rm = fmaxf(rm, __shfl_xor(rm, 32));

  if (__all(rm - m_i <= 11.54f)){
    float rs = 0.f;
    #pragma unroll
    for (int n4 = 0; n4 < 4; ++n4)
      #pragma unroll
      for (int i = 0; i < 4; ++i){
        const float pv = __builtin_amdgcn_exp2f(s[n4][i] - m_i);
        s[n4][i] = pv;
        rs += pv;
      }
    rs += __shfl_xor(rs, 16);
    rs += __shfl_xor(rs, 32);
    l_i += rs;
  } else {
    const float mn = fmaxf(m_i, rm);
    const float sc_ = __builtin_amdgcn_exp2f(m_i - mn);
    m_i = mn;
    float rs = 0.f;
    #pragma unroll
    for (int n4 = 0; n4 < 4; ++n4)
      #pragma unroll
      for (int i = 0; i < 4; ++i){
        const float pv = __builtin_amdgcn_exp2f(s[n4][i] - mn);
        s[n4][i] = pv;
        rs += pv;
      }
    rs += __shfl_xor(rs, 16);
    rs += __shfl_xor(rs, 32);
    l_i = l_i * sc_ + rs;
    #pragma unroll
    for (int n4 = 0; n4 < 4; ++n4)
      #pragma unroll
      for (int i = 0; i < 4; ++i) o[n4][i] *= sc_;
  }

  // P -> wave-local LDS
  #pragma unroll
  for (int n4 = 0; n4 < 4; ++n4){
    const unsigned a = ((unsigned)f2bf_rn(s[n4][0])) | (((unsigned)f2bf_rn(s[n4][1])) << 16);
    const unsigned b = ((unsigned)f2bf_rn(s[n4][2])) | (((unsigned)f2bf_rn(s[n4][3])) << 16);
    const int chunk = (n4*2 + (lgrp >> 1)) ^ (lid & 7);
    const int base = (lid << 6) + (chunk << 3) + ((lgrp & 1) << 2);
    *(unsigned*)&un[base]     = a;
    *(unsigned*)&un[base + 2] = b;
  }

  // drain V loads only now (latency covered by S/E/softmax/P above)
  asm volatile("s_waitcnt vmcnt(0)" ::: "memory");
  __builtin_amdgcn_sched_barrier(0);

  // O^T += V^T P^T
  __builtin_amdgcn_s_setprio(1);
  #pragma unroll
  for (int kk = 0; kk < 2; ++kk){
    const int kc = kk * 4 + lgrp;
    const bf16x8 pb = *(const bf16x8*)&un[(lid << 6) + ((kc ^ (lid & 7)) << 3)];
    #pragma unroll
    for (int n4 = 0; n4 < 4; ++n4){
      const bf16x8 vf = *(const bf16x8*)&Vsb[((n4*16 + lid) << 6) + ((kc ^ (lid & 7)) << 3)];
      o[n4] = MFMA16(vf, pb, o[n4]);
    }
  }
  __builtin_amdgcn_s_setprio(0);
}

__global__ __launch_bounds__(128) void attn_mfma(
    const unsigned short* __restrict__ Y,
    const unsigned short* __restrict__ Vt,
    const unsigned short* __restrict__ BndT,
    unsigned short* __restrict__ AO)
{
  __shared__ unsigned short KV[4][4096];  // K(grp0), K(grp1), V(grp0), V(grp1)
  __shared__ unsigned short UN[2][1600];  // per-wave union: El [80][20] / Pl [16][64]

  const int id = blockIdx.x;
  const int h = id & 15;
  const int u = (id >> 4) & 3;
  const int tid = threadIdx.x;
  const int grp = tid >> 6;               // kv-parity stream (wave id)
  const int lane = tid & 63;
  const int lid = lane & 15, lgrp = lane >> 4;
  const int sr = lane >> 3;
  const int scc = (lane & 7) ^ sr;

  unsigned short* Ksg = &KV[grp][0];
  unsigned short* Vsg = &KV[2 + grp][0];
  unsigned short* un  = &UN[grp][0];

  const int ql = u * 16 + lid;

  #pragma unroll
  for (int seg = 0; seg < 2; ++seg){
    const int qb = seg ? (id >> 6) : (31 - (id >> 6));   // qbA=31-p, qbB=p
    const int q0w = qb * 64 + u * 16;
    const int qrow = q0w + lid;
    const int nt = qb + 1;
    const int L = (nt + 1) >> 1;

    bf16x8 qf[2];
    #pragma unroll
    for (int kk = 0; kk < 2; ++kk)
      qf[kk] = *(const bf16x8*)(Y + (size_t)qrow * LDY2 + h*64 + ((kk*4 + lgrp) << 3));
    bf16x8 rf = {};
    {
      const unsigned* rp = (const unsigned*)(Y + (size_t)qrow * LDY2 + 3072 + h*10);
      if (lgrp == 0){
        #pragma unroll
        for (int x = 0; x < 4; ++x) ((unsigned*)&rf)[x] = rp[x];
      } else if (lgrp == 1){
        ((unsigned*)&rf)[0] = rp[4];
      }
    }

    float m_i = -INFINITY, l_i = 0.f;
    f32x4 o[4] = {};

    for (int it = 0; it < L; ++it){
      const int kb = 2 * it + grp;
      if (kb < nt){
        const int j0 = kb << 6;
        const int d0 = q0w - j0;

        // (1) issue K stage (8 gload_lds)
        #pragma unroll
        for (int st = 0; st < 8; ++st){
          const int r0w = st * 8;
          const int r = r0w + sr;
          __builtin_amdgcn_global_load_lds(
              GLB(Y + (size_t)(j0 + r) * LDY2 + 1024 + h*64 + (scc << 3)),
              LDSP(&Ksg[r0w << 6]), 16, 0, 0);
        }
        __builtin_amdgcn_sched_barrier(0);

        // (2) issue bw loads (5 dwordx4 into VGPRs)
        bf16x8 bw[5];
        #pragma unroll
        for (int f = 0; f < 5; ++f){
          const int rowt = d0 + 1 + f * 16 + lid;     // rel + 64
          bw[f] = *(const bf16x8*)(BndT + ((size_t)rowt << 5) + (lgrp << 3));
        }
        __builtin_amdgcn_sched_barrier(0);

        // (3) issue V stage (8 gload_lds)
        #pragma unroll
        for (int st = 0; st < 8; ++st){
          const int r0w = st * 8;
          const int r = r0w + sr;
          __builtin_amdgcn_global_load_lds(
              GLB(Vt + (size_t)(h*64 + r) * 2048 + j0 + (scc << 3)),
              LDSP(&Vsg[r0w << 6]), 16, 0, 0);
        }
        __builtin_amdgcn_sched_barrier(0);

        // (4) wait for K only (retire oldest 8 of 21): bw+V remain in flight
        asm volatile("s_waitcnt vmcnt(13)" ::: "memory");
        __builtin_amdgcn_sched_barrier(0);

        if (kb == qb)
          attn_tile_body<true >(Ksg, Vsg, un, bw, qf, rf, lid, lgrp, ql, m_i, l_i, o);
        else
          attn_tile_body<false>(Ksg, Vsg, un, bw, qf, rf, lid, lgrp, ql, m_i, l_i, o);
      }
    }

    // ---- exact 2-way merge of the parity streams (in LDS) ----
    float* oScr  = (float*)&KV[1][0];
    float* mlScr = (float*)&KV[3][0];
    if (grp == 1){
      #pragma unroll
      for (int n4 = 0; n4 < 4; ++n4)
        *(f32x4*)&oScr[lid * 64 + n4*16 + lgrp*4] = o[n4];
      if (lgrp == 0){
        mlScr[lid * 2 + 0] = m_i;
        mlScr[lid * 2 + 1] = l_i;
      }
    }
    __syncthreads();
    if (grp == 0){
      const float m1 = mlScr[lid * 2 + 0];
      const float l1 = mlScr[lid * 2 + 1];
      const float M  = fmaxf(m_i, m1);
      const float a  = __builtin_amdgcn_exp2f(m_i - M);
      const float b  = __builtin_amdgcn_exp2f(m1 - M);
      const float inv = 1.f / (l_i * a + l1 * b);
      unsigned short* dst = AO + (size_t)qrow * 1024 + h * 64;
      #pragma unroll
      for (int n4 = 0; n4 < 4; ++n4){
        const f32x4 o1 = *(const f32x4*)&oScr[lid * 64 + n4*16 + lgrp*4];
        const float v0 = (o[n4][0]*a + o1[0]*b) * inv;
        const float v1 = (o[n4][1]*a + o1[1]*b) * inv;
        const float v2 = (o[n4][2]*a + o1[2]*b) * inv;
        const float v3 = (o[n4][3]*a + o1[3]*b) * inv;
        unsigned r0 = ((unsigned)f2bf_rn(v0)) | (((unsigned)f2bf_rn(v1)) << 16);
        unsigned r1 = ((unsigned)f2bf_rn(v2)) | (((unsigned)f2bf_rn(v3)) << 16);
        unsigned long long pk = ((unsigned long long)r1 << 32) | r0;
        *(u64a*)(dst + n4*16 + lgrp*4) = pk;
      }
    }
    __syncthreads();
  }
}

// ---------------- launch ----------------

extern "C" void kernel_launch(void* const* d_in, const int* in_sizes, int n_in,
                              void* d_out, int out_size, void* d_ws, size_t ws_size,
                              hipStream_t stream) {
  const float* X   = (const float*)d_in[0];
  const float* Wq  = (const float*)d_in[1];
  const float* bq  = (const float*)d_in[2];
  const float* Wk  = (const float*)d_in[3];
  const float* Wv  = (const float*)d_in[4];
  const float* Wp  = (const float*)d_in[5];
  const float* bp  = (const float*)d_in[6];
  const float* Wr  = (const float*)d_in[7];
  const float* br  = (const float*)d_in[8];
  const float* bnd = (const float*)d_in[9];
  float* out = (float*)d_out;

  unsigned short* Xb  = (unsigned short*)d_ws;            // 2048*1024 (reused as AO)
  unsigned short* WbT = Xb  + (size_t)2048 * 1024;        // 3328*1024
  unsigned short* Yb  = WbT + (size_t)3328 * 1024;        // 2048*3328
  unsigned short* Vt  = Yb  + (size_t)2048 * 3328;        // 1024*2048
  unsigned short* WpT = Vt  + (size_t)1024 * 2048;        // 1024*1024
  float* bias = (float*)(WpT + (size_t)1024 * 1024);      // 3328
  unsigned short* AO   = Xb;                    // Xb dead after gemm1
  unsigned short* BndT = WbT + (size_t)3232 * 1024;  // WbT pad rows (BndT-only)

  prep_mega <<<2134,         256, 0, stream>>>(X, Wq, Wk, Wv, Wr, Wp, bq, br, bnd,
                                               Xb, WbT, WpT, bias, BndT);
  gemm64    <<<dim3(26, 32), 256, 0, stream>>>(Xb, WbT, bias, Yb, 3328, 0, Vt);
  attn_mfma <<<1024,         128, 0, stream>>>(Yb, Vt, BndT, AO);
  gemm64    <<<dim3(8, 32),  256, 0, stream>>>(AO, WpT, bp, out, 1024, 1, nullptr);
}

// Round 21
// 97.903 us; speedup vs baseline: 1.0134x; 1.0134x over previous
//
#include <hip/hip_runtime.h>
#include <hip/hip_bf16.h>
#include <math.h>

// Problem: B=1, T=2048, E=1024, H=16, DH=64, NB=10, ML=2048
// FINAL (r19 config, session best 98.1us). Pipeline (all bf16 MFMA), 4 kernels:
//   prep_mega: Xb = bf16(X); WbT = [Wq*0.125*log2e|Wk|Wv|Wr]^T (rows<3232);
//              WpT; bias; BndT*log2e (in WbT pad rows - only BndT writes there)
//   gemm64 (64x128, 832 blocks): Y = Xb @ Wb + bias; V-col blocks also emit
//              Vt[h][d][t] transposed in the epilogue
//   attn: independent kv-parity wave-streams (2 waves/block), uniform 17 iters,
//         El [c][20] packed may_alias scratch, exp2 softmax, DIAG templates
//   gemm64 (64x128, 256 blocks): out = AO @ Wp + bp (f32)

typedef __attribute__((ext_vector_type(8))) short bf16x8;
typedef __attribute__((ext_vector_type(4))) float f32x4;
typedef unsigned long long __attribute__((may_alias)) u64a;

#define MFMA16(a,b,c) __builtin_amdgcn_mfma_f32_16x16x32_bf16((a),(b),(c),0,0,0)
#define GLB(p)  ((const __attribute__((address_space(1))) void*)(p))
#define LDSP(p) ((__attribute__((address_space(3))) void*)(p))
#define LDY2 3328
#define LOG2E 1.44269504088896f

__device__ __forceinline__ unsigned short f2bf(float x){
  unsigned u = __float_as_uint(x);
  u = (u + 0x7FFFu + ((u >> 16) & 1u)) >> 16;
  return (unsigned short)u;
}
__device__ __forceinline__ unsigned short f2bf_rn(float x){
  __hip_bfloat16 b = __float2bfloat16(x);
  return *reinterpret_cast<unsigned short*>(&b);
}
__device__ __forceinline__ float bf2f(unsigned short b){
  return __uint_as_float(((unsigned)b) << 16);
}

// -------- prep kernel (convert_x | pack_wbt | transpose_wp | bias | bndt) ----

__global__ __launch_bounds__(256) void prep_mega(
    const float* __restrict__ X,
    const float* __restrict__ Wq, const float* __restrict__ Wk,
    const float* __restrict__ Wv, const float* __restrict__ Wr,
    const float* __restrict__ Wp,
    const float* __restrict__ bq, const float* __restrict__ br,
    const float* __restrict__ bnd,
    unsigned short* __restrict__ Xb, unsigned short* __restrict__ WbT,
    unsigned short* __restrict__ WpT, float* __restrict__ bias,
    unsigned short* __restrict__ BndT)
{
  __shared__ float tile[64][65];
  const int b = blockIdx.x;
  const int tid = threadIdx.x;

  if (b < 1024){
    const int i = (b * 256 + tid) * 8;
    f32x4 a = *(const f32x4*)(X + i);
    f32x4 v2 = *(const f32x4*)(X + i + 4);
    bf16x8 v;
    v[0]=(short)f2bf(a.x); v[1]=(short)f2bf(a.y); v[2]=(short)f2bf(a.z); v[3]=(short)f2bf(a.w);
    v[4]=(short)f2bf(v2.x); v[5]=(short)f2bf(v2.y); v[6]=(short)f2bf(v2.z); v[7]=(short)f2bf(v2.w);
    *(bf16x8*)(Xb + i) = v;
    return;
  }
  if (b < 1024 + 832){
    const int idx = b - 1024;
    const int k0 = (idx & 15) * 64, c0 = (idx >> 4) * 64;
    {
      const int r = tid >> 2, cs = (tid & 3) << 4;
      #pragma unroll
      for (int q = 0; q < 4; ++q){
        const int c = c0 + cs + q * 4;
        f32x4 v;
        if (c < 1024){
          v = *(const f32x4*)(Wq + (size_t)(k0+r)*1024 + c);
          const float s = 0.125f * LOG2E;   // fold 1/sqrt(d) and log2e into Q
          v.x *= s; v.y *= s; v.z *= s; v.w *= s;
        }
        else if (c < 2048) v = *(const f32x4*)(Wk + (size_t)(k0+r)*1024 + (c-1024));
        else if (c < 3072) v = *(const f32x4*)(Wv + (size_t)(k0+r)*1024 + (c-2048));
        else if (c < 3232) v = *(const f32x4*)(Wr + (size_t)(k0+r)*160  + (c-3072));
        else               v = (f32x4){0.f,0.f,0.f,0.f};
        tile[r][cs+q*4+0]=v.x; tile[r][cs+q*4+1]=v.y; tile[r][cs+q*4+2]=v.z; tile[r][cs+q*4+3]=v.w;
      }
    }
    __syncthreads();
    const int c = tid >> 2, ks = (tid & 3) << 4;
    if (c0 + c < 3232){     // rows >= 3232 belong to BndT (written elsewhere)
      bf16x8 o0, o1;
      #pragma unroll
      for (int x = 0; x < 8; ++x) o0[x] = (short)f2bf(tile[ks + x][c]);
      #pragma unroll
      for (int x = 0; x < 8; ++x) o1[x] = (short)f2bf(tile[ks + 8 + x][c]);
      *(bf16x8*)(WbT + (size_t)(c0 + c) * 1024 + k0 + ks)     = o0;
      *(bf16x8*)(WbT + (size_t)(c0 + c) * 1024 + k0 + ks + 8) = o1;
    }
    return;
  }
  if (b < 1024 + 832 + 256){
    const int idx = b - 1856;
    const int k0 = (idx & 15) * 64, c0 = (idx >> 4) * 64;
    {
      const int r = tid >> 2, cs = (tid & 3) << 4;
      #pragma unroll
      for (int q = 0; q < 4; ++q){
        f32x4 v = *(const f32x4*)(Wp + (size_t)(k0+r)*1024 + c0 + cs + q*4);
        tile[r][cs+q*4+0]=v.x; tile[r][cs+q*4+1]=v.y; tile[r][cs+q*4+2]=v.z; tile[r][cs+q*4+3]=v.w;
      }
    }
    __syncthreads();
    const int c = tid >> 2, ks = (tid & 3) << 4;
    bf16x8 o0, o1;
    #pragma unroll
    for (int x = 0; x < 8; ++x) o0[x] = (short)f2bf(tile[ks + x][c]);
    #pragma unroll
    for (int x = 0; x < 8; ++x) o1[x] = (short)f2bf(tile[ks + 8 + x][c]);
    *(bf16x8*)(WpT + (size_t)(c0 + c) * 1024 + k0 + ks)     = o0;
    *(bf16x8*)(WpT + (size_t)(c0 + c) * 1024 + k0 + ks + 8) = o1;
    return;
  }
  if (b < 2125){
    const int c = (b - 2112) * 256 + tid;
    if (c < 3328){
      float v = 0.f;
      if (c < 1024) v = bq[c] * 0.125f * LOG2E;
      else if (c >= 3072 && c < 3232) v = br[c - 3072];
      bias[c] = v;
    }
    return;
  }
  // BndT[t'][32] scaled by log2e; t' = rel + 64 in [0,2176)
  const int t = (b - 2125) * 256 + tid;
  if (t >= 2176) return;
  const int rel = t - 64;
  unsigned short* dst = BndT + (size_t)t * 32;
  bf16x8 v0 = {}, v1 = {}, z = {};
  if (rel >= 0 && rel < 2048){
    #pragma unroll
    for (int n = 0; n < 8; ++n) v0[n] = (short)f2bf(bnd[n * 2048 + rel] * LOG2E);
    v1[0] = (short)f2bf(bnd[8 * 2048 + rel] * LOG2E);
    v1[1] = (short)f2bf(bnd[9 * 2048 + rel] * LOG2E);
  }
  *(bf16x8*)dst        = v0;
  *(bf16x8*)(dst + 8)  = v1;
  *(bf16x8*)(dst + 16) = z;
  *(bf16x8*)(dst + 24) = z;
}

// ---------------- bf16 MFMA GEMM, 64x128 tile (unified) ---------------------
// If VtOut != nullptr, blocks covering cols [2048,3072) also store the tile
// transposed: Vt[(col-2048)*2048 + row] (replaces the vt_transpose pass).

__global__ __launch_bounds__(256) void gemm64(
    const unsigned short* __restrict__ A,
    const unsigned short* __restrict__ BT,
    const float* __restrict__ bias,
    void* __restrict__ C, int ldc, int out_f32,
    unsigned short* __restrict__ VtOut)
{
  __shared__ unsigned short As[64 * 64];
  __shared__ unsigned short Bs[128 * 64];
  const int tid = threadIdx.x;
  const int w = tid >> 6, lane = tid & 63;
  const int lid = lane & 15, lgrp = lane >> 4;
  const int wm = w >> 1, wn = w & 1;
  const int row0 = blockIdx.y << 6, col0 = blockIdx.x << 7;
  const int sr = lane >> 3;
  const int sc = (lane & 7) ^ sr;
  const bool do_vt = (VtOut != nullptr) && (col0 >= 2048) && (col0 < 3072);

  f32x4 acc[2][4] = {};

  for (int k0 = 0; k0 < 1024; k0 += 64){
    #pragma unroll
    for (int it = 0; it < 2; ++it){
      const int r0w = (w << 4) + (it << 3);
      const int r = r0w + sr;
      __builtin_amdgcn_global_load_lds(GLB(A + (size_t)(row0 + r) * 1024 + k0 + (sc << 3)),
                                       LDSP(&As[r0w << 6]), 16, 0, 0);
    }
    #pragma unroll
    for (int it = 0; it < 4; ++it){
      const int r0w = (w << 5) + (it << 3);
      const int r = r0w + sr;
      __builtin_amdgcn_global_load_lds(GLB(BT + (size_t)(col0 + r) * 1024 + k0 + (sc << 3)),
                                       LDSP(&Bs[r0w << 6]), 16, 0, 0);
    }
    __syncthreads();

    bf16x8 af[2][2], bfr[4][2];
    #pragma unroll
    for (int m = 0; m < 2; ++m){
      const int ra = wm * 32 + m * 16 + lid;
      #pragma unroll
      for (int kk = 0; kk < 2; ++kk){
        const int kc = kk * 4 + lgrp;
        af[m][kk] = *(const bf16x8*)&As[(ra << 6) + ((kc ^ (lid & 7)) << 3)];
      }
    }
    #pragma unroll
    for (int n = 0; n < 4; ++n){
      const int rb = wn * 64 + n * 16 + lid;
      #pragma unroll
      for (int kk = 0; kk < 2; ++kk){
        const int kc = kk * 4 + lgrp;
        bfr[n][kk] = *(const bf16x8*)&Bs[(rb << 6) + ((kc ^ (lid & 7)) << 3)];
      }
    }
    #pragma unroll
    for (int m = 0; m < 2; ++m)
      #pragma unroll
      for (int n = 0; n < 4; ++n){
        acc[m][n] = MFMA16(af[m][0], bfr[n][0], acc[m][n]);
        acc[m][n] = MFMA16(af[m][1], bfr[n][1], acc[m][n]);
      }
    __syncthreads();
  }

  #pragma unroll
  for (int m = 0; m < 2; ++m){
    #pragma unroll
    for (int n = 0; n < 4; ++n){
      const int col = col0 + wn * 64 + n * 16 + lid;
      const float bv = bias[col];
      const int rowb = row0 + wm * 32 + m * 16 + lgrp * 4;
      unsigned short bf[4];
      #pragma unroll
      for (int i = 0; i < 4; ++i){
        const float v = acc[m][n][i] + bv;
        if (out_f32) ((float*)C)[(size_t)(rowb + i) * ldc + col] = v;
        else {
          bf[i] = f2bf(v);
          ((unsigned short*)C)[(size_t)(rowb + i) * ldc + col] = bf[i];
        }
      }
      if (do_vt){
        // Vt[(col-2048)*2048 + row], 4 consecutive rows -> one 8B store
        const unsigned long long pk =
            ((unsigned long long)bf[0])        | (((unsigned long long)bf[1]) << 16) |
            (((unsigned long long)bf[2]) << 32) | (((unsigned long long)bf[3]) << 48);
        *(u64a*)(VtOut + (size_t)(col - 2048) * 2048 + rowb) = pk;
      }
    }
  }
}

// ---------------- fused flash attention (r18 + DIAG specialization) ----------

__device__ __forceinline__ void stage_tile(
    const unsigned short* __restrict__ Y,
    const unsigned short* __restrict__ Vt,
    unsigned short* __restrict__ Ksb,
    unsigned short* __restrict__ Vsb,
    int j0, int h, int sr, int scc)
{
  #pragma unroll
  for (int st = 0; st < 8; ++st){
    const int r0w = st * 8;
    const int r = r0w + sr;
    __builtin_amdgcn_global_load_lds(
        GLB(Y + (size_t)(j0 + r) * LDY2 + 1024 + h*64 + (scc << 3)),
        LDSP(&Ksb[r0w << 6]), 16, 0, 0);
    __builtin_amdgcn_global_load_lds(
        GLB(Vt + (size_t)(h*64 + r) * 2048 + j0 + (scc << 3)),
        LDSP(&Vsb[r0w << 6]), 16, 0, 0);
  }
}

template<bool DIAG>
__device__ __forceinline__ void attn_tile_body(
    const unsigned short* __restrict__ Ksb,
    const unsigned short* __restrict__ Vsb,
    unsigned short* __restrict__ un,
    const bf16x8 (&bw)[5],
    const bf16x8 (&qf)[2], const bf16x8& rf,
    int lid, int lgrp, int ql,
    float& m_i, float& l_i, f32x4 (&o)[4])
{
  // S^T = K Q^T : s[n4][i] = S[q=lid][j = n4*16 + lgrp*4 + i]  (exp2 domain)
  f32x4 s[4] = {};
  __builtin_amdgcn_s_setprio(1);
  #pragma unroll
  for (int kk = 0; kk < 2; ++kk){
    const int kc = kk * 4 + lgrp;
    #pragma unroll
    for (int n4 = 0; n4 < 4; ++n4){
      const bf16x8 kf = *(const bf16x8*)&Ksb[((n4*16 + lid) << 6) + ((kc ^ (lid & 7)) << 3)];
      s[n4] = MFMA16(kf, qf[kk], s[n4]);
    }
  }
  __builtin_amdgcn_s_setprio(0);

  // E window via MFMA; scratch el[c][20], one b64 may_alias write per f
  #pragma unroll
  for (int f = 0; f < 5; ++f){
    f32x4 ef = {};
    ef = MFMA16(rf, bw[f], ef);
    const unsigned lo = ((unsigned)f2bf_rn(ef[0])) | (((unsigned)f2bf_rn(ef[1])) << 16);
    const unsigned hi = ((unsigned)f2bf_rn(ef[2])) | (((unsigned)f2bf_rn(ef[3])) << 16);
    const unsigned long long pk = ((unsigned long long)hi << 32) | lo;
    *(u64a*)&un[(f*16 + lid) * 20 + lgrp*4] = pk;
  }

  // bias gather (+ causal mask only on the diagonal tile)
  #pragma unroll
  for (int n4 = 0; n4 < 4; ++n4){
    #pragma unroll
    for (int i = 0; i < 4; ++i){
      const int jl = n4*16 + lgrp*4 + i;
      float v = s[n4][i] + bf2f(un[(lid - jl + 63) * 20 + lid]);
      if (DIAG && jl > ql) v = -1e9f;
      s[n4][i] = v;
    }
  }

  // in-register online softmax (exp2 domain), defer-max THR = 8*log2e
  float rm = s[0][0];
  #pragma unroll
  for (int n4 = 0; n4 < 4; ++n4)
    #pragma unroll
    for (int i = 0; i < 4; ++i) rm = fmaxf(rm, s[n4][i]);
  rm = fmaxf(rm, __shfl_xor(rm, 16));
  rm = fmaxf(rm, __shfl_xor(rm, 32));

  if (__all(rm - m_i <= 11.54f)){
    float rs = 0.f;
    #pragma unroll
    for (int n4 = 0; n4 < 4; ++n4)
      #pragma unroll
      for (int i = 0; i < 4; ++i){
        const float pv = __builtin_amdgcn_exp2f(s[n4][i] - m_i);
        s[n4][i] = pv;
        rs += pv;
      }
    rs += __shfl_xor(rs, 16);
    rs += __shfl_xor(rs, 32);
    l_i += rs;
  } else {
    const float mn = fmaxf(m_i, rm);
    const float sc_ = __builtin_amdgcn_exp2f(m_i - mn);
    m_i = mn;
    float rs = 0.f;
    #pragma unroll
    for (int n4 = 0; n4 < 4; ++n4)
      #pragma unroll
      for (int i = 0; i < 4; ++i){
        const float pv = __builtin_amdgcn_exp2f(s[n4][i] - mn);
        s[n4][i] = pv;
        rs += pv;
      }
    rs += __shfl_xor(rs, 16);
    rs += __shfl_xor(rs, 32);
    l_i = l_i * sc_ + rs;
    #pragma unroll
    for (int n4 = 0; n4 < 4; ++n4)
      #pragma unroll
      for (int i = 0; i < 4; ++i) o[n4][i] *= sc_;
  }

  // P -> wave-local LDS (union region; el reads above complete first)
  #pragma unroll
  for (int n4 = 0; n4 < 4; ++n4){
    const unsigned a = ((unsigned)f2bf_rn(s[n4][0])) | (((unsigned)f2bf_rn(s[n4][1])) << 16);
    const unsigned b = ((unsigned)f2bf_rn(s[n4][2])) | (((unsigned)f2bf_rn(s[n4][3])) << 16);
    const int chunk = (n4*2 + (lgrp >> 1)) ^ (lid & 7);
    const int base = (lid << 6) + (chunk << 3) + ((lgrp & 1) << 2);
    *(unsigned*)&un[base]     = a;
    *(unsigned*)&un[base + 2] = b;
  }

  // O^T += V^T P^T
  __builtin_amdgcn_s_setprio(1);
  #pragma unroll
  for (int kk = 0; kk < 2; ++kk){
    const int kc = kk * 4 + lgrp;
    const bf16x8 pb = *(const bf16x8*)&un[(lid << 6) + ((kc ^ (lid & 7)) << 3)];
    #pragma unroll
    for (int n4 = 0; n4 < 4; ++n4){
      const bf16x8 vf = *(const bf16x8*)&Vsb[((n4*16 + lid) << 6) + ((kc ^ (lid & 7)) << 3)];
      o[n4] = MFMA16(vf, pb, o[n4]);
    }
  }
  __builtin_amdgcn_s_setprio(0);
}

__global__ __launch_bounds__(128) void attn_mfma(
    const unsigned short* __restrict__ Y,
    const unsigned short* __restrict__ Vt,
    const unsigned short* __restrict__ BndT,
    unsigned short* __restrict__ AO)
{
  __shared__ unsigned short KV[4][4096];  // K(grp0), K(grp1), V(grp0), V(grp1)
  __shared__ unsigned short UN[2][1600];  // per-wave union: El [80][20] / Pl [16][64]

  const int id = blockIdx.x;
  const int h = id & 15;
  const int u = (id >> 4) & 3;            // quarter within the 64-row block
  const int tid = threadIdx.x;
  const int grp = tid >> 6;               // kv-parity stream (wave id)
  const int lane = tid & 63;
  const int lid = lane & 15, lgrp = lane >> 4;
  const int sr = lane >> 3;
  const int scc = (lane & 7) ^ sr;

  unsigned short* Ksg = &KV[grp][0];
  unsigned short* Vsg = &KV[2 + grp][0];
  unsigned short* un  = &UN[grp][0];

  const int ql = u * 16 + lid;            // local-64 q (same both segments)

  #pragma unroll
  for (int seg = 0; seg < 2; ++seg){
    const int qb = seg ? (id >> 6) : (31 - (id >> 6));   // qbA=31-p, qbB=p
    const int q0w = qb * 64 + u * 16;
    const int qrow = q0w + lid;
    const int nt = qb + 1;
    const int L = (nt + 1) >> 1;

    // loop-invariant fragments for this segment
    bf16x8 qf[2];
    #pragma unroll
    for (int kk = 0; kk < 2; ++kk)
      qf[kk] = *(const bf16x8*)(Y + (size_t)qrow * LDY2 + h*64 + ((kk*4 + lgrp) << 3));
    bf16x8 rf = {};
    {
      const unsigned* rp = (const unsigned*)(Y + (size_t)qrow * LDY2 + 3072 + h*10);
      if (lgrp == 0){
        #pragma unroll
        for (int x = 0; x < 4; ++x) ((unsigned*)&rf)[x] = rp[x];
      } else if (lgrp == 1){
        ((unsigned*)&rf)[0] = rp[4];
      }
    }

    float m_i = -INFINITY, l_i = 0.f;
    f32x4 o[4] = {};

    // independent per-wave kv stream: tiles kb = grp, grp+2, ...
    for (int it = 0; it < L; ++it){
      const int kb = 2 * it + grp;
      if (kb < nt){
        const int j0 = kb << 6;
        const int d0 = q0w - j0;

        stage_tile(Y, Vt, Ksg, Vsg, j0, h, sr, scc);

        bf16x8 bw[5];
        #pragma unroll
        for (int f = 0; f < 5; ++f){
          const int rowt = d0 + 1 + f * 16 + lid;     // rel + 64
          bw[f] = *(const bf16x8*)(BndT + ((size_t)rowt << 5) + (lgrp << 3));
        }

        asm volatile("s_waitcnt vmcnt(0)" ::: "memory");
        __builtin_amdgcn_sched_barrier(0);

        if (kb == qb)
          attn_tile_body<true >(Ksg, Vsg, un, bw, qf, rf, lid, lgrp, ql, m_i, l_i, o);
        else
          attn_tile_body<false>(Ksg, Vsg, un, bw, qf, rf, lid, lgrp, ql, m_i, l_i, o);
      }
    }

    // ---- exact 2-way merge of the parity streams (in LDS) ----
    float* oScr  = (float*)&KV[1][0];     // 16 q x 64 d f32 (grp1's K buf)
    float* mlScr = (float*)&KV[3][0];     // 16 q x 2 f32 (grp1's V buf)
    if (grp == 1){
      #pragma unroll
      for (int n4 = 0; n4 < 4; ++n4)
        *(f32x4*)&oScr[lid * 64 + n4*16 + lgrp*4] = o[n4];
      if (lgrp == 0){
        mlScr[lid * 2 + 0] = m_i;
        mlScr[lid * 2 + 1] = l_i;
      }
    }
    __syncthreads();
    if (grp == 0){
      const float m1 = mlScr[lid * 2 + 0];
      const float l1 = mlScr[lid * 2 + 1];
      const float M  = fmaxf(m_i, m1);
      const float a  = __builtin_amdgcn_exp2f(m_i - M);
      const float b  = __builtin_amdgcn_exp2f(m1 - M);
      const float inv = 1.f / (l_i * a + l1 * b);
      unsigned short* dst = AO + (size_t)qrow * 1024 + h * 64;
      #pragma unroll
      for (int n4 = 0; n4 < 4; ++n4){
        const f32x4 o1 = *(const f32x4*)&oScr[lid * 64 + n4*16 + lgrp*4];
        const float v0 = (o[n4][0]*a + o1[0]*b) * inv;
        const float v1 = (o[n4][1]*a + o1[1]*b) * inv;
        const float v2 = (o[n4][2]*a + o1[2]*b) * inv;
        const float v3 = (o[n4][3]*a + o1[3]*b) * inv;
        unsigned r0 = ((unsigned)f2bf_rn(v0)) | (((unsigned)f2bf_rn(v1)) << 16);
        unsigned r1 = ((unsigned)f2bf_rn(v2)) | (((unsigned)f2bf_rn(v3)) << 16);
        unsigned long long pk = ((unsigned long long)r1 << 32) | r0;
        *(u64a*)(dst + n4*16 + lgrp*4) = pk;
      }
    }
    __syncthreads();   // scratch (KV[1]/KV[3]) free before next segment staging
  }
}

// ---------------- launch ----------------

extern "C" void kernel_launch(void* const* d_in, const int* in_sizes, int n_in,
                              void* d_out, int out_size, void* d_ws, size_t ws_size,
                              hipStream_t stream) {
  const float* X   = (const float*)d_in[0];
  const float* Wq  = (const float*)d_in[1];
  const float* bq  = (const float*)d_in[2];
  const float* Wk  = (const float*)d_in[3];
  const float* Wv  = (const float*)d_in[4];
  const float* Wp  = (const float*)d_in[5];
  const float* bp  = (const float*)d_in[6];
  const float* Wr  = (const float*)d_in[7];
  const float* br  = (const float*)d_in[8];
  const float* bnd = (const float*)d_in[9];
  float* out = (float*)d_out;

  unsigned short* Xb  = (unsigned short*)d_ws;            // 2048*1024 (reused as AO)
  unsigned short* WbT = Xb  + (size_t)2048 * 1024;        // 3328*1024
  unsigned short* Yb  = WbT + (size_t)3328 * 1024;        // 2048*3328
  unsigned short* Vt  = Yb  + (size_t)2048 * 3328;        // 1024*2048
  unsigned short* WpT = Vt  + (size_t)1024 * 2048;        // 1024*1024
  float* bias = (float*)(WpT + (size_t)1024 * 1024);      // 3328
  unsigned short* AO   = Xb;                    // Xb dead after gemm1
  unsigned short* BndT = WbT + (size_t)3232 * 1024;  // WbT pad rows (BndT-only)

  prep_mega <<<2134,         256, 0, stream>>>(X, Wq, Wk, Wv, Wr, Wp, bq, br, bnd,
                                               Xb, WbT, WpT, bias, BndT);
  gemm64    <<<dim3(26, 32), 256, 0, stream>>>(Xb, WbT, bias, Yb, 3328, 0, Vt);
  attn_mfma <<<1024,         128, 0, stream>>>(Yb, Vt, BndT, AO);
  gemm64    <<<dim3(8, 32),  256, 0, stream>>>(AO, WpT, bp, out, 1024, 1, nullptr);
}